// Round 11
// baseline (515.826 us; speedup 1.0000x reference)
//
#include <hip/hip_runtime.h>
#include <math.h>

// TreeAttention: hierarchical top-k mask refinement + sparse attention.
// N=8, T_DST=512, T_SRC=4096, HID=64, K=64, W0=64, SCALE_UP=2, OVERSAMPLE=1.5
//
// Round 10 design (resubmitted round 11 — round 10 lost to container infra
// failure; kernel audited: no barrier-divergence hang path, no OOB, all
// cross-wave LDS races are identical-value word-atomic writes).
// TWO WAVES PER ROW (8192 waves = 32 waves/CU, the full machine).
// Round 8/9 lesson: the backend pins a 64-VGPR budget and spills deep
// per-thread batches -> get latency hiding from WAVES, not per-thread ILP.
//  - element e = sub*64+lane, ONE candidate per lane (was 2).
//  - 3x __syncthreads per iter for cross-wave LDS visibility; scan and
//    enumerate run redundantly in both waves (identical writes, benign).
//  - dot: rotation-4 float4 scalars (16 regs, 4 loads in flight, no spill).
//  - rank: 4-deep uint4 LDS broadcast batches.
//  - final: sub0 softmax; PV split j 0..31 / 32..63, LDS partial combine.
//  - __launch_bounds__(256, 8): exactly the 64-VGPR budget we can afford.

#define TSRC_N 4096
#define HID_N  64
#define NEGV   -32000.0f

__global__ __launch_bounds__(256, 8)
void tree_attn_kernel(const float* __restrict__ q,
                      const float* __restrict__ k,
                      const float* __restrict__ v,
                      float* __restrict__ out)
{
    const int wid4 = __builtin_amdgcn_readfirstlane((int)(threadIdx.x >> 6)); // 0..3
    const int lane = threadIdx.x & 63;
    const int pairid = wid4 >> 1;          // row within block (0,1)
    const int sub    = wid4 & 1;           // element-half (0,1)
    const int row  = (blockIdx.x << 1) + pairid;   // 0..4095, wave-uniform
    const int n    = row >> 9;
    const float tsrc = (float)(3585 + (row & 511));
    const int e    = (sub << 6) + lane;    // my candidate element 0..127

    __shared__ __align__(16) unsigned int key_s[2][128];
    __shared__ __align__(16) unsigned int bm_s[2][128];   // 4096-bit bitmaps
    __shared__ int                        pix_s[2][128];
    __shared__ unsigned char              msk_s[2][128];
    __shared__ __align__(8) unsigned int  pp_s[2][128];   // {p_bits, pix}
    __shared__ float                      part_s[2][64];  // PV partials

    unsigned int*  const keyw  = key_s[pairid];
    unsigned int*  const bmw   = bm_s[pairid];
    int*           const pixw  = pix_s[pairid];
    unsigned char* const mskw  = msk_s[pairid];
    unsigned int*  const ppw   = pp_s[pairid];
    float*         const partw = part_s[pairid];

    const float* qrow = q + (size_t)row * HID_N;   // uniform -> s_load
    const float* kb   = k + (size_t)n * TSRC_N * HID_N;
    const float* vb   = v + (size_t)n * TSRC_N * HID_N;

    // f32 dot with 4-deep rotating float4 window (16 VGPRs, 4 loads in flight)
    auto dot_f32 = [&](int tx) -> float {
        const float4* k4 = (const float4*)(kb + (size_t)tx * HID_N);
        float4 c0 = k4[0], c1 = k4[1], c2 = k4[2], c3 = k4[3];
        float a0 = 0.f, a1 = 0.f, a2 = 0.f, a3 = 0.f;
        #pragma unroll
        for (int g = 0; g < 4; ++g) {
            float4 n0, n1, n2, n3;
            if (g < 3) {
                n0 = k4[4*g+4]; n1 = k4[4*g+5]; n2 = k4[4*g+6]; n3 = k4[4*g+7];
            }
            const float* qg = qrow + 16*g;
            a0 = fmaf(c0.x, qg[0],  a0);  a1 = fmaf(c0.y, qg[1],  a1);
            a2 = fmaf(c0.z, qg[2],  a2);  a3 = fmaf(c0.w, qg[3],  a3);
            a0 = fmaf(c1.x, qg[4],  a0);  a1 = fmaf(c1.y, qg[5],  a1);
            a2 = fmaf(c1.z, qg[6],  a2);  a3 = fmaf(c1.w, qg[7],  a3);
            a0 = fmaf(c2.x, qg[8],  a0);  a1 = fmaf(c2.y, qg[9],  a1);
            a2 = fmaf(c2.z, qg[10], a2);  a3 = fmaf(c2.w, qg[11], a3);
            a0 = fmaf(c3.x, qg[12], a0);  a1 = fmaf(c3.y, qg[13], a1);
            a2 = fmaf(c3.z, qg[14], a2);  a3 = fmaf(c3.w, qg[15], a3);
            if (g < 3) { c0 = n0; c1 = n1; c2 = n2; c3 = n3; }
        }
        return (a0 + a1) + (a2 + a3);
    };
    // order-preserving f32 -> u32 flip (key 0 reserved for absent slots)
    auto flip32 = [](float s) -> unsigned int {
        const unsigned int u = __float_as_uint(s);
        return u ^ ((unsigned)((int)u >> 31) | 0x80000000u);
    };

    // iteration 0 state: pixels = arange(96), pmask = arange(96) < 64
    pixw[e] = e;
    mskw[e] = (e < 64) ? 1 : 0;
    __syncthreads();

    float ws = 64.0f;
    int Z = 96;

    for (int it = 0; it < 7; ++it) {
        const bool  last    = (it == 6);
        const float mult    = last ? 1.0f : 1.5f;
        const int   tks_max = (it == 0) ? 63 : (last ? 64 : 96);
        const int   max_z   = last ? 64 : 128;

        // ---- score -> u32 key (one element per lane) ----
        const float r = tsrc / ws;                 // exact f32 (pow2 ratio or 1)
        unsigned int mykey = 0;
        int myp = 0;
        if (e < Z) {
            float sc = NEGV;
            myp = pixw[e];
            if (mskw[e]) {
                int tx = (int)rintf((float)myp * r); // exact product, half-even
                tx = tx < (TSRC_N - 1) ? tx : (TSRC_N - 1);
                sc = dot_f32(tx);
            }
            mykey = flip32(sc);
        }
        keyw[e] = mykey;
        bmw[e]  = 0u;
        __syncthreads();                           // sync1

        // ---- rank: count strictly-greater keys (broadcast uint4 reads) ----
        int rank = 0;
        #pragma unroll
        for (int j = 0; j < 128; j += 16) {
            const uint4 a = *(const uint4*)&keyw[j];
            const uint4 b = *(const uint4*)&keyw[j + 4];
            const uint4 c = *(const uint4*)&keyw[j + 8];
            const uint4 d = *(const uint4*)&keyw[j + 12];
            rank += (int)(a.x > mykey) + (int)(a.y > mykey)
                  + (int)(a.z > mykey) + (int)(a.w > mykey)
                  + (int)(b.x > mykey) + (int)(b.y > mykey)
                  + (int)(b.z > mykey) + (int)(b.w > mykey)
                  + (int)(c.x > mykey) + (int)(c.y > mykey)
                  + (int)(c.z > mykey) + (int)(c.w > mykey)
                  + (int)(d.x > mykey) + (int)(d.y > mykey)
                  + (int)(d.z > mykey) + (int)(d.w > mykey);
        }

        // ---- tks = clip(round(ws/tsrc * 64 * mult), 1, min(ws-1, Z-1)) ----
        float x = ws / tsrc;
        x *= 64.0f;
        x *= mult;
        float t = rintf(x);
        t = fmaxf(1.0f, fminf(t, fminf(ws - 1.0f, (float)(Z - 1))));
        const int tks = (int)t;

        const float ws_new = fminf(tsrc, ws * 2.0f);
        const float scale  = ws_new / ws;     // 2.0, tsrc/2048, or 1.0 (exact)

        // ---- scatter next-scale values into the bitmap ----
        if (e == 0) atomicOr(&bmw[0], 1u);    // padded top-k slots -> value 0
        if (e < Z && rank < tks_max) {
            int s0 = (int)rintf((float)myp * scale);
            s0 = s0 < (TSRC_N - 1) ? s0 : (TSRC_N - 1);
            atomicOr(&bmw[s0 >> 5], 1u << (s0 & 31));
            if (rank < tks) {
                const int s1i = (int)rintf((float)(myp + 1) * scale);
                if (s1i - s0 >= 2) {
                    const int c2 = s0 + 1;
                    atomicOr(&bmw[c2 >> 5], 1u << (c2 & 31));
                }
            }
        }
        __syncthreads();                           // sync2

        // ---- exclusive prefix of popcounts (redundant in both waves) ----
        const uint2 w2 = *(const uint2*)&bmw[2 * lane];
        const int cnt = __popc(w2.x) + __popc(w2.y);
        int scan = cnt;
        #pragma unroll
        for (int off = 1; off < 64; off <<= 1) {
            const int o = __shfl_up(scan, off);
            if (lane >= off) scan += o;
        }
        int pref = scan - cnt;                // exclusive prefix
        // clear next-state (each wave clears its half; both halves covered)
        pixw[e] = 0;
        mskw[e] = 0;
        __syncthreads();                           // sync3

        // ---- enumerate ascending set bits (redundant, identical writes) ----
        unsigned int wv = w2.x;
        int base = lane << 6;                 // word 2L covers values 64L..
        while (wv) {
            if (pref >= max_z) break;
            const int b = __ffs(wv) - 1;
            wv &= wv - 1u;
            pixw[pref] = base + b;
            mskw[pref] = 1;
            ++pref;
        }
        wv = w2.y;
        base += 32;
        while (wv) {
            if (pref >= max_z) break;
            const int b = __ffs(wv) - 1;
            wv &= wv - 1u;
            pixw[pref] = base + b;
            mskw[pref] = 1;
            ++pref;
        }
        __builtin_amdgcn_wave_barrier();      // own-wave LDS order before reuse

        ws = ws_new;
        Z  = max_z;
    }

    // ---- final scores + softmax (sub==0 wave; 64 pixels, one per lane) ----
    if (sub == 0) {
        const int pixf = pixw[lane];
        float sfin = -1e30f;
        if (mskw[lane]) sfin = dot_f32(pixf);
        float m = sfin;
        #pragma unroll
        for (int off = 32; off > 0; off >>= 1)
            m = fmaxf(m, __shfl_xor(m, off));
        const float ex = __expf(sfin - m);    // masked -> 0
        float ssum = ex;
        #pragma unroll
        for (int off = 32; off > 0; off >>= 1)
            ssum += __shfl_xor(ssum, off);
        const float p = ex / ssum;
        ppw[2 * lane]     = __float_as_uint(p);
        ppw[2 * lane + 1] = (unsigned int)pixf;
    }
    __syncthreads();

    // ---- PV split: sub0 sums j=0..31, sub1 sums j=32..63 ----
    float acc = 0.f;
    {
        const unsigned int* pbase = ppw + (sub << 6);   // &ppw[2*(sub*32)]
        #pragma unroll
        for (int j0 = 0; j0 < 32; j0 += 4) {
            const uint2 p0 = *(const uint2*)&pbase[2 * j0];
            const uint2 p1 = *(const uint2*)&pbase[2 * j0 + 2];
            const uint2 p2 = *(const uint2*)&pbase[2 * j0 + 4];
            const uint2 p3 = *(const uint2*)&pbase[2 * j0 + 6];
            const float v0 = vb[(size_t)p0.y * HID_N + lane];
            const float v1 = vb[(size_t)p1.y * HID_N + lane];
            const float v2 = vb[(size_t)p2.y * HID_N + lane];
            const float v3 = vb[(size_t)p3.y * HID_N + lane];
            acc = fmaf(__uint_as_float(p0.x), v0, acc);
            acc = fmaf(__uint_as_float(p1.x), v1, acc);
            acc = fmaf(__uint_as_float(p2.x), v2, acc);
            acc = fmaf(__uint_as_float(p3.x), v3, acc);
        }
    }
    if (sub == 1) partw[lane] = acc;
    __syncthreads();
    if (sub == 0) out[(size_t)row * HID_N + lane] = acc + partw[lane];
}

extern "C" void kernel_launch(void* const* d_in, const int* in_sizes, int n_in,
                              void* d_out, int out_size, void* d_ws, size_t ws_size,
                              hipStream_t stream) {
    const float* q = (const float*)d_in[0];
    const float* k = (const float*)d_in[1];
    const float* v = (const float*)d_in[2];
    float* out = (float*)d_out;
    const int rows = in_sizes[0] / HID_N;   // N * T_DST = 4096
    tree_attn_kernel<<<(rows + 1) / 2, 256, 0, stream>>>(q, k, v, out);
}

// Round 13
// 207.486 us; speedup vs baseline: 2.4861x; 2.4861x over previous
//
#include <hip/hip_runtime.h>
#include <math.h>

// TreeAttention: hierarchical top-k mask refinement + sparse attention.
// N=8, T_DST=512, T_SRC=4096, HID=64, K=64, W0=64, SCALE_UP=2, OVERSAMPLE=1.5
//
// Round 12 design (resubmitted round 13 — round 12 lost to broker timeout).
// COOPERATIVE DOT on the round-7 structure (107us known-good:
// 4 rows/block, 1 wave/row, private LDS slices, wave_barrier only).
// Round 11's 883MB FETCH == per-dot q re-reads + uncached k gathers at
// VGPR=32. Fix the dot itself:
//  - 8 lanes per candidate; lane sl=lane&7 holds q[8sl..8sl+7] in 8 VGPRs
//    loaded ONCE per kernel (zero repeated q traffic).
//  - per pass: 8-lane group reads one k row as 8x32B contiguous chunks
//    (coalesced), 8 FMA, 3 shfl_xor levels; 16 passes cover 128 candidates.
//  - low per-pass VGPR use -> scheduler pipelines passes (MLP from
//    independence, not from spill-prone batching arrays).
// Rank/scatter/scan/enumerate/PV phases: identical to round 7.

#define TSRC_N 4096
#define HID_N  64
#define NEGV   -32000.0f

__global__ __launch_bounds__(256)
void tree_attn_kernel(const float* __restrict__ q,
                      const float* __restrict__ k,
                      const float* __restrict__ v,
                      float* __restrict__ out)
{
    const int wid  = __builtin_amdgcn_readfirstlane((int)(threadIdx.x >> 6));
    const int lane = threadIdx.x & 63;
    const int row  = (blockIdx.x << 2) + wid;      // 0..4095, wave-uniform
    const int n    = row >> 9;
    const float tsrc = (float)(3585 + (row & 511));
    const int sg = lane >> 3;          // candidate subgroup 0..7
    const int sl = lane & 7;           // slice within candidate row

    // per-wave private LDS slices — no cross-wave sharing, no __syncthreads
    __shared__ __align__(16) unsigned int key_s[4][128];
    __shared__ __align__(16) unsigned int bm_s[4][128];   // 4096-bit bitmaps
    __shared__ int                        pix_s[4][128];
    __shared__ unsigned char              msk_s[4][128];
    __shared__ __align__(8) unsigned int  pp_s[4][128];   // {p_bits, pix}
    unsigned int*  const keyw = key_s[wid];
    unsigned int*  const bmw  = bm_s[wid];
    int*           const pixw = pix_s[wid];
    unsigned char* const mskw = msk_s[wid];
    unsigned int*  const ppw  = pp_s[wid];

    const float* qrow = q + (size_t)row * HID_N;
    const float* kb   = k + (size_t)n * TSRC_N * HID_N;
    const float* vb   = v + (size_t)n * TSRC_N * HID_N;

    // my q slice, loaded once, lives in 8 VGPRs for the whole kernel
    const float4 q0 = ((const float4*)qrow)[2 * sl];
    const float4 q1 = ((const float4*)qrow)[2 * sl + 1];

    // cooperative partial dot for row tx: my 32B slice, then 8-lane reduce
    auto coop_dot = [&](int tx) -> float {
        const float4* kp = (const float4*)(kb + (size_t)tx * HID_N) + 2 * sl;
        const float4 k0 = kp[0];
        const float4 k1 = kp[1];
        float a0 = fmaf(k0.x, q0.x, k0.y * q0.y);
        float a1 = fmaf(k0.z, q0.z, k0.w * q0.w);
        a0 = fmaf(k1.x, q1.x, a0);
        a1 = fmaf(k1.y, q1.y, a1);
        a0 = fmaf(k1.z, q1.z, a0);
        a1 = fmaf(k1.w, q1.w, a1);
        float s = a0 + a1;
        s += __shfl_xor(s, 1);
        s += __shfl_xor(s, 2);
        s += __shfl_xor(s, 4);
        return s;                       // all 8 lanes hold the full dot
    };
    // order-preserving f32 -> u32 flip (key 0 reserved for absent slots)
    auto flip32 = [](float s) -> unsigned int {
        const unsigned int u = __float_as_uint(s);
        return u ^ ((unsigned)((int)u >> 31) | 0x80000000u);
    };

    // iteration 0 state: pixels = arange(96), pmask = arange(96) < 64
    pixw[lane]      = lane;
    pixw[lane + 64] = lane + 64;
    mskw[lane]      = 1;
    mskw[lane + 64] = 0;
    __builtin_amdgcn_wave_barrier();

    float ws = 64.0f;
    int Z = 96;

    for (int it = 0; it < 7; ++it) {
        const bool  last    = (it == 6);
        const float mult    = last ? 1.0f : 1.5f;
        const int   tks_max = (it == 0) ? 63 : (last ? 64 : 96);
        const int   max_z   = last ? 64 : 128;

        // ---- cooperative scores -> u32 keys (8 lanes per candidate) ----
        const float r = tsrc / ws;                 // exact f32 (pow2 ratio or 1)
        #pragma unroll 4
        for (int p = 0; p < 16; ++p) {
            const int c = (p << 3) + sg;           // candidate index
            unsigned int key = 0;
            if (c < Z) {                           // uniform within 8-group
                float sc = NEGV;
                if (mskw[c]) {                     // broadcast byte read
                    int tx = (int)rintf((float)pixw[c] * r);
                    tx = tx < (TSRC_N - 1) ? tx : (TSRC_N - 1);
                    sc = coop_dot(tx);
                }
                key = flip32(sc);
            }
            if (sl == 0) keyw[c] = key;            // 8 writers, stride-1
        }
        bmw[lane]      = 0u;
        bmw[lane + 64] = 0u;
        __builtin_amdgcn_wave_barrier();

        // ---- ranks: lane owns candidates lane and lane+64 ----
        const unsigned int key0 = keyw[lane];
        const unsigned int key1 = keyw[lane + 64];
        int r0 = 0, r1 = 0;
        #pragma unroll
        for (int j = 0; j < 128; j += 16) {
            const uint4 a = *(const uint4*)&keyw[j];
            const uint4 b = *(const uint4*)&keyw[j + 4];
            const uint4 c = *(const uint4*)&keyw[j + 8];
            const uint4 d = *(const uint4*)&keyw[j + 12];
            r0 += (int)(a.x > key0) + (int)(a.y > key0)
                + (int)(a.z > key0) + (int)(a.w > key0)
                + (int)(b.x > key0) + (int)(b.y > key0)
                + (int)(b.z > key0) + (int)(b.w > key0)
                + (int)(c.x > key0) + (int)(c.y > key0)
                + (int)(c.z > key0) + (int)(c.w > key0)
                + (int)(d.x > key0) + (int)(d.y > key0)
                + (int)(d.z > key0) + (int)(d.w > key0);
            r1 += (int)(a.x > key1) + (int)(a.y > key1)
                + (int)(a.z > key1) + (int)(a.w > key1)
                + (int)(b.x > key1) + (int)(b.y > key1)
                + (int)(b.z > key1) + (int)(b.w > key1)
                + (int)(c.x > key1) + (int)(c.y > key1)
                + (int)(c.z > key1) + (int)(c.w > key1)
                + (int)(d.x > key1) + (int)(d.y > key1)
                + (int)(d.z > key1) + (int)(d.w > key1);
        }

        // ---- tks = clip(round(ws/tsrc * 64 * mult), 1, min(ws-1, Z-1)) ----
        float x = ws / tsrc;
        x *= 64.0f;
        x *= mult;
        float t = rintf(x);
        t = fmaxf(1.0f, fminf(t, fminf(ws - 1.0f, (float)(Z - 1))));
        const int tks = (int)t;

        const float ws_new = fminf(tsrc, ws * 2.0f);
        const float scale  = ws_new / ws;     // 2.0, tsrc/2048, or 1.0 (exact)

        // ---- scatter next-scale values into the bitmap ----
        if (lane == 0) atomicOr(&bmw[0], 1u); // padded top-k slots -> value 0
        if (r0 < tks_max) {
            const int p0 = pixw[lane];
            int s0 = (int)rintf((float)p0 * scale);
            s0 = s0 < (TSRC_N - 1) ? s0 : (TSRC_N - 1);
            atomicOr(&bmw[s0 >> 5], 1u << (s0 & 31));
            if (r0 < tks) {
                const int s1i = (int)rintf((float)(p0 + 1) * scale);
                if (s1i - s0 >= 2) {
                    const int c2 = s0 + 1;
                    atomicOr(&bmw[c2 >> 5], 1u << (c2 & 31));
                }
            }
        }
        if (lane + 64 < Z && r1 < tks_max) {
            const int p1 = pixw[lane + 64];
            int s0 = (int)rintf((float)p1 * scale);
            s0 = s0 < (TSRC_N - 1) ? s0 : (TSRC_N - 1);
            atomicOr(&bmw[s0 >> 5], 1u << (s0 & 31));
            if (r1 < tks) {
                const int s1i = (int)rintf((float)(p1 + 1) * scale);
                if (s1i - s0 >= 2) {
                    const int c2 = s0 + 1;
                    atomicOr(&bmw[c2 >> 5], 1u << (c2 & 31));
                }
            }
        }
        __builtin_amdgcn_wave_barrier();

        // ---- exclusive prefix of popcounts; lane owns words 2L, 2L+1 ----
        const uint2 w2 = *(const uint2*)&bmw[2 * lane];
        const int cnt = __popc(w2.x) + __popc(w2.y);
        int scan = cnt;
        #pragma unroll
        for (int off = 1; off < 64; off <<= 1) {
            const int o = __shfl_up(scan, off);
            if (lane >= off) scan += o;
        }
        int pref = scan - cnt;                // exclusive prefix
        pixw[lane] = 0;  pixw[lane + 64] = 0;
        mskw[lane] = 0;  mskw[lane + 64] = 0;
        __builtin_amdgcn_wave_barrier();

        // ---- enumerate ascending set bits == sort+dedup, first max_z ----
        unsigned int wv = w2.x;
        int base = lane << 6;                 // word 2L covers values 64L..
        while (wv) {
            if (pref >= max_z) break;
            const int b = __ffs(wv) - 1;
            wv &= wv - 1u;
            pixw[pref] = base + b;
            mskw[pref] = 1;
            ++pref;
        }
        wv = w2.y;
        base += 32;
        while (wv) {
            if (pref >= max_z) break;
            const int b = __ffs(wv) - 1;
            wv &= wv - 1u;
            pixw[pref] = base + b;
            mskw[pref] = 1;
            ++pref;
        }
        __builtin_amdgcn_wave_barrier();

        ws = ws_new;
        Z  = max_z;
    }

    // ---- final scores (cooperative, 8 passes) -> raw floats in keyw ----
    #pragma unroll 4
    for (int p = 0; p < 8; ++p) {
        const int c = (p << 3) + sg;
        float sc = -1e30f;
        if (mskw[c]) sc = coop_dot(pixw[c]);
        if (sl == 0) keyw[c] = __float_as_uint(sc);
    }
    __builtin_amdgcn_wave_barrier();

    // ---- softmax over 64 scores (one per lane) ----
    {
        const float sfin = __uint_as_float(keyw[lane]);
        float m = sfin;
        #pragma unroll
        for (int off = 32; off > 0; off >>= 1)
            m = fmaxf(m, __shfl_xor(m, off));
        const float ex = __expf(sfin - m);    // masked -> 0
        float ssum = ex;
        #pragma unroll
        for (int off = 32; off > 0; off >>= 1)
            ssum += __shfl_xor(ssum, off);
        const float pr = ex / ssum;
        ppw[2 * lane]     = __float_as_uint(pr);
        ppw[2 * lane + 1] = (unsigned int)pixw[lane];
    }
    __builtin_amdgcn_wave_barrier();

    // ---- PV: p-weighted gather of v rows (coalesced per j) ----
    {
        float acc = 0.f;
        #pragma unroll 4
        for (int j0 = 0; j0 < 64; j0 += 4) {
            const uint2 p0 = *(const uint2*)&ppw[2 * j0];
            const uint2 p1 = *(const uint2*)&ppw[2 * j0 + 2];
            const uint2 p2 = *(const uint2*)&ppw[2 * j0 + 4];
            const uint2 p3 = *(const uint2*)&ppw[2 * j0 + 6];
            const float v0 = vb[(size_t)p0.y * HID_N + lane];
            const float v1 = vb[(size_t)p1.y * HID_N + lane];
            const float v2 = vb[(size_t)p2.y * HID_N + lane];
            const float v3 = vb[(size_t)p3.y * HID_N + lane];
            acc = fmaf(__uint_as_float(p0.x), v0, acc);
            acc = fmaf(__uint_as_float(p1.x), v1, acc);
            acc = fmaf(__uint_as_float(p2.x), v2, acc);
            acc = fmaf(__uint_as_float(p3.x), v3, acc);
        }
        out[(size_t)row * HID_N + lane] = acc;
    }
}

extern "C" void kernel_launch(void* const* d_in, const int* in_sizes, int n_in,
                              void* d_out, int out_size, void* d_ws, size_t ws_size,
                              hipStream_t stream) {
    const float* q = (const float*)d_in[0];
    const float* k = (const float*)d_in[1];
    const float* v = (const float*)d_in[2];
    float* out = (float*)d_out;
    const int rows = in_sizes[0] / HID_N;   // N * T_DST = 4096
    tree_attn_kernel<<<(rows + 3) / 4, 256, 0, stream>>>(q, k, v, out);
}